// Round 1
// 77.467 us; speedup vs baseline: 1.0047x; 1.0047x over previous
//
#include <hip/hip_runtime.h>

#define NQ 10
#define TS 10
#define DIM 1024
#define ND 1024

typedef _Float16 h4 __attribute__((ext_vector_type(4)));
typedef __fp16  p2 __attribute__((ext_vector_type(2)));   // cvt_pkrtz result type
typedef float f4 __attribute__((ext_vector_type(4)));

// D = A*B + C, 16x16x16 f16 -> f32 (layout facts verified in R12):
//   C/D: (row,col) at lane = col + 16*(row>>2), reg = row&3
//   A:   (m,k)     at lane = m  + 16*(k>>2),   slot = k&3
//   B:   (k,n)     at lane = n  + 16*(k>>2),   slot = k&3
// => a stored C-tile read as A gives its TRANSPOSE; read as B gives itself.
__device__ __forceinline__ f4 mfma16(h4 a, h4 b, f4 c) {
    return __builtin_amdgcn_mfma_f32_16x16x16f16(a, b, c, 0, 0, 0);
}
__device__ __forceinline__ h4 cvt_h4(f4 x) {
    p2 lo = __builtin_amdgcn_cvt_pkrtz(x[0], x[1]);
    p2 hi = __builtin_amdgcn_cvt_pkrtz(x[2], x[3]);
    h4 r; r[0] = lo[0]; r[1] = lo[1]; r[2] = hi[0]; r[3] = hi[1];
    return r;
}
// conditional sign flip via precomputed xor mask (exact, 1 v_xor)
__device__ __forceinline__ float xsgn(float v, unsigned m) {
    return __uint_as_float(__float_as_uint(v) ^ m);
}

// One wave per sample. State P[r][l'] (16x64) in MFMA C/D layout as 4
// col-tiles. R15 pipeline kept: iter t ISSUES phi loads for step t+2 and
// CONSUMES step t+1's phis. NEW this round:
//  - gb/hb double-buffered + prep moved between G and H stages (kills the
//    WAR hazard that serialized tile-build against the H-stage MFMA reads)
//  - hsel chains replaced by hoisted lane masks + xor-sign (1-2 insts each)
//  - hb built as outer product: hb[n][j][s] = +/- P[idx]*W[s]; the 4x4 TP
//    products are shared and the compile-time sign folds into cvt_pkrtz's
//    source-neg modifier (exact -> no extra f16 rounding vs previous kernel)
//  - diag apply in f4 vector form (v_pk_mul/fma_f32), H chains split 4->2
__global__ __launch_bounds__(64, 1) void qsim_kernel(
    const float* __restrict__ re_in, const float* __restrict__ im_in,
    const float* __restrict__ phis, const float* __restrict__ gs,
    float* __restrict__ out)
{
    const int sample = blockIdx.x;
    const int lane = threadIdx.x;
    const int quad = lane >> 4;
    const int cc = lane & 15;
    const int c3 = (cc >> 3) & 1, c2 = (cc >> 2) & 1, c1 = (cc >> 1) & 1, c0 = cc & 1;
    const int q1 = quad >> 1, q0 = quad & 1;

    // hoisted per-lane selection state (reused every step, ~20 hsels/step)
    const bool e31 = (c3 == q1);
    const bool e20 = (c2 == q0);
    const bool bc1 = (c1 != 0);
    const bool bc0 = (c0 != 0);
    const unsigned sg3 = c3 ? 0u : 0x80000000u;   // sign of S-branch when ob=c3
    const unsigned sg2 = c2 ? 0u : 0x80000000u;

    const float* pr_in = re_in + sample * DIM;
    const float* pi_in = im_in + sample * DIM;
    const float* ph = phis + sample * (3 * NQ * TS);
    const float* gsp = gs + sample * TS;

    // ---- load state into fragment layout ----
    f4 Sr[4], Si[4];
    const int lbase = 256 * quad + cc;
#pragma unroll
    for (int n = 0; n < 4; ++n)
#pragma unroll
        for (int s = 0; s < 4; ++s) {
            Sr[n][s] = pr_in[lbase + 64 * s + 16 * n];
            Si[n][s] = pi_in[lbase + 64 * s + 16 * n];
        }

    const float inv = 0.15811388300841897f;  // 1/(2*sqrt(10))
    float gk[TS];
#pragma unroll
    for (int t = 0; t < TS; ++t) gk[t] = -0.5f * (gsp[t] * inv);

    // ---- normalize ----
    float nrm = 0.f;
#pragma unroll
    for (int n = 0; n < 4; ++n)
#pragma unroll
        for (int s = 0; s < 4; ++s) nrm += Sr[n][s] * Sr[n][s] + Si[n][s] * Si[n][s];
#pragma unroll
    for (int off = 32; off >= 1; off >>= 1) nrm += __shfl_xor(nrm, off, 64);
    const float scl = rsqrtf(nrm);
#pragma unroll
    for (int n = 0; n < 4; ++n) { Sr[n] *= scl; Si[n] *= scl; }

    // ---- static pairsum per element ----
    float psv[4][4];
    const int pbase = __popc(quad) + __popc(cc);
#pragma unroll
    for (int n = 0; n < 4; ++n)
#pragma unroll
        for (int s = 0; s < 4; ++s) {
            const int p = pbase + __popc(n) + __popc(s);
            const int z = NQ - 2 * p;
            psv[n][s] = 0.5f * (float)(z * z - NQ);
        }
    const float fq1 = (float)q1, fq0 = (float)q0;
    const float fc3 = (float)c3, fc2 = (float)c2, fc1 = (float)c1, fc0 = (float)c0;

    // diag trig buffers (single-buffered: consumed at TOP of next step, so
    // the write during this step has no WAR against live MFMA reads)
    f4 DCPv[4], DSPv[4];
    // gate tiles DOUBLE-buffered: H-stage reads buf[tt&1] while prep writes
    // buf[(tt+1)&1] -> scheduler can interleave prep VALU with MFMA latency
    h4 gbb[2];
    h4 hbb[2][4][4];
    float bcur[NQ];

    // diag-trig (state-independent) -> DCPv/DSPv
    auto make_trig = [&](const float* v, float kcur) {
        float sv = 0.f;
#pragma unroll
        for (int i = 0; i < NQ; ++i) sv += v[i];
        float base = -0.5f * sv;
        base = fmaf(fq1, v[0], base); base = fmaf(fq0, v[1], base);
        base = fmaf(fc3, v[6], base); base = fmaf(fc2, v[7], base);
        base = fmaf(fc1, v[8], base); base = fmaf(fc0, v[9], base);
        const float addS[4] = {0.f, v[3], v[2], v[2] + v[3]};
        const float addN[4] = {0.f, v[5], v[4], v[4] + v[5]};
#pragma unroll
        for (int n = 0; n < 4; ++n)
#pragma unroll
            for (int s = 0; s < 4; ++s) {
                const float phi = fmaf(kcur, psv[n][s], base + addN[n] + addS[s]);
                float sp, cp;
                __sincosf(phi, &sp, &cp);
                DCPv[n][s] = cp;
                DSPv[n][s] = sp;
            }
    };

    // build gate tiles from th_src (10 thetas)
    // hsel(ob,ib,c,s) = (ob==ib)? c : (ob? s : -s), specialized:
    //   both runtime (ob=c3,ib=q1):  e31 ? C : xsgn(S, sg3)
    //   runtime ob, ib==0:           ob ? S : C
    //   runtime ob, ib==1:           ob ? C : -S
    //   both compile-time (F45):     pure +/- sign on {CC,CS,SC,SS}
    auto make_tiles = [&](const float* th, h4& gbo, h4 (&hbo)[4][4]) {
        float C[NQ], S[NQ];
#pragma unroll
        for (int g = 0; g < NQ; ++g) {
            float sg, cg;
            __sincosf(0.5f * th[g], &sg, &cg);
            S[g] = sg; C[g] = cg;
        }
        // ---- row gate gbo (qubits 0-3) ----
        {
            const float g0 = e31 ? C[0] : xsgn(S[0], sg3);
            const float g1 = e20 ? C[1] : xsgn(S[1], sg2);
            const float f01 = g0 * g1;
            const float A0 = bc1 ? S[2] : C[2];
            const float A1 = bc1 ? C[2] : -S[2];
            const float B0 = bc0 ? S[3] : C[3];
            const float B1 = bc0 ? C[3] : -S[3];
            p2 lo = __builtin_amdgcn_cvt_pkrtz(f01 * A0 * B0, f01 * A0 * B1);
            p2 hi = __builtin_amdgcn_cvt_pkrtz(f01 * A1 * B0, f01 * A1 * B1);
            gbo[0] = lo[0]; gbo[1] = lo[1]; gbo[2] = hi[0]; gbo[3] = hi[1];
        }
        // ---- col gate hbo (qubits 4-9), outer-product form ----
        const float F67 = (e31 ? C[6] : xsgn(S[6], sg3)) * (e20 ? C[7] : xsgn(S[7], sg2));
        const float A0p = bc1 ? S[8] : C[8];
        const float A1p = bc1 ? C[8] : -S[8];
        const float B0p = bc0 ? S[9] : C[9];
        const float B1p = bc0 ? C[9] : -S[9];
        float W[4];
        W[0] = F67 * A0p * B0p; W[1] = F67 * A0p * B1p;
        W[2] = F67 * A1p * B0p; W[3] = F67 * A1p * B1p;
        const float P4[4] = {C[4] * C[5], C[4] * S[5], S[4] * C[5], S[4] * S[5]};
        float TP[4][4];
#pragma unroll
        for (int k = 0; k < 4; ++k)
#pragma unroll
            for (int s = 0; s < 4; ++s) TP[k][s] = P4[k] * W[s];
#pragma unroll
        for (int n = 0; n < 4; ++n)
#pragma unroll
            for (int j = 0; j < 4; ++j) {
                const int n1 = n >> 1, n0 = n & 1, j1 = j >> 1, j0 = j & 1;
                const int d1 = n1 ^ j1, d0 = n0 ^ j0;
                const int idx = d1 * 2 + d0;
                // val4 negative iff (n1,j1)==(0,1); val5 negative iff (n0,j0)==(0,1)
                const float sg = (((d1 && !n1) ? -1.f : 1.f) * ((d0 && !n0) ? -1.f : 1.f));
                p2 lo = __builtin_amdgcn_cvt_pkrtz(sg * TP[idx][0], sg * TP[idx][1]);
                p2 hi = __builtin_amdgcn_cvt_pkrtz(sg * TP[idx][2], sg * TP[idx][3]);
                hbo[n][j][0] = lo[0]; hbo[n][j][1] = lo[1];
                hbo[n][j][2] = hi[0]; hbo[n][j][3] = hi[1];
            }
    };

    // ---- prologue: step-0 prep (direct), then load step-1 phis into pipe[0] ----
    {
        float phs0[30];
#pragma unroll
        for (int j = 0; j < 30; ++j) phs0[j] = ph[j];
        make_trig(&phs0[0], 0.f);               // v0 = a0 (b(-1)=0), k=0
        make_tiles(&phs0[10], gbb[0], hbb[0]);
#pragma unroll
        for (int i = 0; i < NQ; ++i) bcur[i] = phs0[20 + i];
    }
    float pipe[2][30];
#pragma unroll
    for (int j = 0; j < 30; ++j) pipe[0][j] = ph[30 + j];   // phis(step 1)

    const f4 zf4 = {0.f, 0.f, 0.f, 0.f};

#pragma unroll
    for (int tt = 0; tt < TS; ++tt) {
        // ---- 1. boundary diagonal (f4 vector form -> v_pk_mul/fma_f32) ----
#pragma unroll
        for (int n = 0; n < 4; ++n) {
            const f4 xr = Sr[n], xi = Si[n];
            Sr[n] = DCPv[n] * xr - DSPv[n] * xi;
            Si[n] = DSPv[n] * xr + DCPv[n] * xi;
        }

        // ---- 2. ISSUE loads for step tt+2 (consumed 1.5 iterations later) ----
        if (tt + 2 < TS) {
#pragma unroll
            for (int j = 0; j < 30; ++j) pipe[(tt + 1) & 1][j] = ph[30 * (tt + 2) + j];
        }

        // ---- 3. cvt state + G-stage ----
        h4 ar[4], ai[4];
#pragma unroll
        for (int n = 0; n < 4; ++n) { ar[n] = cvt_h4(Sr[n]); ai[n] = cvt_h4(Si[n]); }
        f4 Tr[4], Ti[4];
#pragma unroll
        for (int n = 0; n < 4; ++n) {
            Tr[n] = mfma16(ar[n], gbb[tt & 1], zf4);
            Ti[n] = mfma16(ai[n], gbb[tt & 1], zf4);
        }

        // ---- 4. prep step tt+1 into the OTHER buffers (no WAR vs H-stage
        //         reads of buf[tt&1] -> interleaves with MFMA latency) ----
        if (tt + 1 < TS) {
            const float* pN = pipe[tt & 1];
            float vN[NQ];
#pragma unroll
            for (int i = 0; i < NQ; ++i) vN[i] = pN[i] + bcur[i];
            make_trig(vN, gk[tt]);
            make_tiles(&pN[10], gbb[(tt + 1) & 1], hbb[(tt + 1) & 1]);
#pragma unroll
            for (int i = 0; i < NQ; ++i) bcur[i] = pN[20 + i];
        } else {
            make_trig(bcur, gk[TS - 1]);   // trailing diagonal
        }

        // ---- 5. cvt T + H-stage, accumulation chains split 4 -> 2+2 ----
        h4 tr[4], ti[4];
#pragma unroll
        for (int n = 0; n < 4; ++n) { tr[n] = cvt_h4(Tr[n]); ti[n] = cvt_h4(Ti[n]); }
#pragma unroll
        for (int n = 0; n < 4; ++n) {
            f4 r0 = mfma16(tr[0], hbb[tt & 1][n][0], zf4);
            r0 = mfma16(tr[1], hbb[tt & 1][n][1], r0);
            f4 r1 = mfma16(tr[2], hbb[tt & 1][n][2], zf4);
            r1 = mfma16(tr[3], hbb[tt & 1][n][3], r1);
            f4 i0 = mfma16(ti[0], hbb[tt & 1][n][0], zf4);
            i0 = mfma16(ti[1], hbb[tt & 1][n][1], i0);
            f4 i1 = mfma16(ti[2], hbb[tt & 1][n][2], zf4);
            i1 = mfma16(ti[3], hbb[tt & 1][n][3], i1);
            Sr[n] = r0 + r1;
            Si[n] = i0 + i1;
        }
    }

    // ---- trailing diagonal ----
#pragma unroll
    for (int n = 0; n < 4; ++n) {
        const f4 xr = Sr[n], xi = Si[n];
        Sr[n] = DCPv[n] * xr - DSPv[n] * xi;
        Si[n] = DSPv[n] * xr + DCPv[n] * xi;
    }

    float* outr = out + sample * DIM;
    float* outi = out + ND * DIM + sample * DIM;
#pragma unroll
    for (int n = 0; n < 4; ++n)
#pragma unroll
        for (int s = 0; s < 4; ++s) {
            outr[lbase + 64 * s + 16 * n] = Sr[n][s];
            outi[lbase + 64 * s + 16 * n] = Si[n][s];
        }
}

extern "C" void kernel_launch(void* const* d_in, const int* in_sizes, int n_in,
                              void* d_out, int out_size, void* d_ws, size_t ws_size,
                              hipStream_t stream) {
    const float* re_in = (const float*)d_in[0];
    const float* im_in = (const float*)d_in[1];
    const float* phis  = (const float*)d_in[2];
    const float* gs    = (const float*)d_in[3];
    float* out = (float*)d_out;
    qsim_kernel<<<ND, 64, 0, stream>>>(re_in, im_in, phis, gs, out);
}